// Round 1
// baseline (314.904 us; speedup 1.0000x reference)
//
#include <hip/hip_runtime.h>

typedef __bf16 bf16;
typedef __bf16 bf16x4 __attribute__((ext_vector_type(4)));
typedef __bf16 bf16x8 __attribute__((ext_vector_type(8)));
typedef float f32x4 __attribute__((ext_vector_type(4)));

#define NTOK 49
#define HW 56
#define SHIFT3 3
constexpr float kScale = 0.17677669529663687f;  // 32^-0.5

// ws layout (bytes, 16B aligned)
#define WS_BIAS  0        // f32 [4*49*64]   = 50176 B
#define WS_QKVW  50176    // bf16[384*128]   = 98304 B
#define WS_PROJW 148480   // bf16[128*128]   = 32768 B
#define WS_FC1W  181248   // bf16[512*128]   = 131072 B
#define WS_FC2W  312320   // bf16[128*512]   = 131072 B

static __device__ __forceinline__ f32x4 mfma16(bf16x8 a, bf16x8 b, f32x4 c) {
    return __builtin_amdgcn_mfma_f32_16x16x32_bf16(a, b, c, 0, 0, 0);
}

// ---------------- setup kernels ----------------

__global__ void bias_kernel(const float* __restrict__ rel_table,
                            const int* __restrict__ rel_index,
                            float* __restrict__ biasbuf) {
    int idx = blockIdx.x * 256 + threadIdx.x;     // over 4*49*64 = 12544
    if (idx >= 4 * NTOK * 64) return;
    int j = idx & 63;
    int rest = idx >> 6;
    int i = rest % NTOK;
    int h = rest / NTOK;
    float v = -1e30f;                             // masks j >= 49 (K padding)
    if (j < NTOK) v = rel_table[rel_index[i * NTOK + j] * 4 + h];
    biasbuf[idx] = v;
}

__global__ void wcvt_kernel(const float* __restrict__ qkv_w, const float* __restrict__ proj_w,
                            const float* __restrict__ fc1_w, const float* __restrict__ fc2_w,
                            bf16* __restrict__ qkvw, bf16* __restrict__ projw,
                            bf16* __restrict__ fc1w, bf16* __restrict__ fc2w) {
    int idx = blockIdx.x * 256 + threadIdx.x;     // grid covers 196608 exactly
    if (idx < 49152)        qkvw[idx]          = (bf16)qkv_w[idx];
    else if (idx < 65536)   projw[idx - 49152] = (bf16)proj_w[idx - 49152];
    else if (idx < 131072)  fc1w[idx - 65536]  = (bf16)fc1_w[idx - 65536];
    else                    fc2w[idx - 131072] = (bf16)fc2_w[idx - 131072];
}

// ---------------- fused attention (per-window) ----------------
// block = one 7x7 window; 4 waves = 4 heads. LDS 64KB -> 2 blocks/CU.

__global__ __launch_bounds__(256, 2) void attn_kernel(
    const float* __restrict__ x,
    const float* __restrict__ n1w, const float* __restrict__ n1b,
    const bf16*  __restrict__ qkvw, const float* __restrict__ qkv_b,
    const bf16*  __restrict__ projw, const float* __restrict__ proj_b,
    const float* __restrict__ biasbuf,
    float* __restrict__ yout)
{
    __shared__ __align__(16) char smem[65536];
    bf16* const hb = (bf16*)smem;                       // h / ao: [64][128] bf16, 256B rows

    const int tid  = threadIdx.x;
    const int wave = tid >> 6;
    const int lane = tid & 63;
    const int g = lane >> 4;     // 0..3 (k-chunk group)
    const int c = lane & 15;     // 0..15

    char* const qbase  = smem + 16384 + wave * 8192;    // q [64][32] 64B rows
    char* const kbase  = qbase + 4096;                  // k [64][32]
    char* const pbase  = qbase;                         // P [64][64] 128B rows (overlays q+k)
    char* const vtbase = smem + 49152 + wave * 4096;    // vT [32][64] 128B rows

    const int w  = blockIdx.x;
    const int b  = w >> 6;
    const int wi = (w >> 3) & 7;
    const int wj = w & 7;
    const int head = wave;

    // ---- stage 0: LN1 + shifted-window gather -> hb (rows 49..63 zeroed) ----
    {
        const int slot = tid >> 5, l32 = tid & 31;
        for (int it = 0; it < 8; ++it) {
            int t  = slot + (it << 3);                  // 0..63
            int tt = t < NTOK ? t : NTOK - 1;
            int r  = tt / 7, cc = tt - r * 7;
            int row = wi * 7 + r + SHIFT3;  if (row >= HW) row -= HW;
            int col = wj * 7 + cc + SHIFT3; if (col >= HW) col -= HW;
            const float* src = x + (((size_t)(b * 3136 + row * 56 + col)) << 7) + (l32 << 2);
            float4 v = *(const float4*)src;
            float s  = v.x + v.y + v.z + v.w;
            float s2 = v.x * v.x + v.y * v.y + v.z * v.z + v.w * v.w;
            for (int m = 1; m <= 16; m <<= 1) {         // reduce within 32-lane group
                s  += __shfl_xor(s,  m, 64);
                s2 += __shfl_xor(s2, m, 64);
            }
            float mean = s * (1.0f / 128.0f);
            float var  = s2 * (1.0f / 128.0f) - mean * mean;
            float rs   = rsqrtf(var + 1e-5f);
            float4 wv = *(const float4*)(n1w + (l32 << 2));
            float4 bv = *(const float4*)(n1b + (l32 << 2));
            bf16x4 outv;
            if (t < NTOK) {
                outv[0] = (bf16)((v.x - mean) * rs * wv.x + bv.x);
                outv[1] = (bf16)((v.y - mean) * rs * wv.y + bv.y);
                outv[2] = (bf16)((v.z - mean) * rs * wv.z + bv.z);
                outv[3] = (bf16)((v.w - mean) * rs * wv.w + bv.w);
            } else {
                outv[0] = (bf16)0.0f; outv[1] = (bf16)0.0f;
                outv[2] = (bf16)0.0f; outv[3] = (bf16)0.0f;
            }
            int off = (l32 << 3) ^ ((t & 7) << 4);      // swizzled byte off in 256B row
            *(bf16x4*)((char*)hb + t * 256 + off) = outv;
        }
    }
    __syncthreads();

    // ---- stage 1: qkv = h @ Wqkv^T (per head), MFMA 16x16x32 ----
    f32x4 fz = {0.f, 0.f, 0.f, 0.f};
    f32x4 qa[4][2], ka[4][2], va[4][2];
    for (int mt = 0; mt < 4; ++mt)
        for (int nt = 0; nt < 2; ++nt) { qa[mt][nt] = fz; ka[mt][nt] = fz; va[mt][nt] = fz; }

    for (int ks = 0; ks < 4; ++ks) {
        bf16x8 af[4];
        const int koff = ks * 64 + g * 16;              // byte offset within 256B row
        for (int mt = 0; mt < 4; ++mt) {
            int row = mt * 16 + c;
            af[mt] = *(const bf16x8*)((char*)hb + row * 256 + (koff ^ ((row & 7) << 4)));
        }
        for (int nt = 0; nt < 2; ++nt) {
            int jq  = head * 32 + nt * 16 + c;          // out-channel within Q block
            int kel = ks * 32 + g * 8;                  // k-dim element offset
            bf16x8 bq = *(const bf16x8*)(qkvw + (size_t)jq * 128 + kel);
            bf16x8 bk = *(const bf16x8*)(qkvw + (size_t)(128 + jq) * 128 + kel);
            bf16x8 bv = *(const bf16x8*)(qkvw + (size_t)(256 + jq) * 128 + kel);
            for (int mt = 0; mt < 4; ++mt) {
                qa[mt][nt] = mfma16(af[mt], bq, qa[mt][nt]);
                ka[mt][nt] = mfma16(af[mt], bk, ka[mt][nt]);
                va[mt][nt] = mfma16(af[mt], bv, va[mt][nt]);
            }
        }
    }
    // store q,k (row-major [64][32]) and v transposed (vT [32][64]); +qkv bias
    for (int nt = 0; nt < 2; ++nt) {
        int dl = nt * 16 + c;                           // 0..31
        float bq = qkv_b[head * 32 + dl];
        float bk = qkv_b[128 + head * 32 + dl];
        float bv = qkv_b[256 + head * 32 + dl];
        for (int mt = 0; mt < 4; ++mt)
            for (int r = 0; r < 4; ++r) {
                int tok = mt * 16 + g * 4 + r;          // C-frag row
                *(bf16*)(qbase + tok * 64 + ((dl * 2) ^ ((tok & 3) << 4))) = (bf16)(qa[mt][nt][r] + bq);
                *(bf16*)(kbase + tok * 64 + ((dl * 2) ^ ((tok & 3) << 4))) = (bf16)(ka[mt][nt][r] + bk);
                *(bf16*)(vtbase + dl * 128 + ((tok * 2) ^ ((dl & 7) << 4))) = (bf16)(va[mt][nt][r] + bv);
            }
    }
    __syncthreads();   // all h reads done (hb reused for ao below)

    // ---- stage 2: S = q k^T (K=32, one MFMA step) ----
    f32x4 s[4][4];
    for (int mt = 0; mt < 4; ++mt) for (int nt = 0; nt < 4; ++nt) s[mt][nt] = fz;
    {
        bf16x8 aq[4];
        for (int mt = 0; mt < 4; ++mt) {
            int row = mt * 16 + c;
            aq[mt] = *(const bf16x8*)(qbase + row * 64 + ((g * 16) ^ ((row & 3) << 4)));
        }
        for (int nt = 0; nt < 4; ++nt) {
            int row = nt * 16 + c;
            bf16x8 bk = *(const bf16x8*)(kbase + row * 64 + ((g * 16) ^ ((row & 3) << 4)));
            for (int mt = 0; mt < 4; ++mt) s[mt][nt] = mfma16(aq[mt], bk, s[mt][nt]);
        }
    }

    // ---- stage 3: softmax rows (bias includes -1e30 mask at j>=49) ----
    const float* bbase = biasbuf + head * (NTOK * 64);
    float lsum[4][4];
    for (int mt = 0; mt < 4; ++mt) {
        for (int r = 0; r < 4; ++r) {
            int i  = mt * 16 + g * 4 + r;
            int im = i < NTOK ? i : NTOK - 1;
            const float* brow = bbase + im * 64 + c;
            float sv[4];
            float mx = -3e38f;
            for (int nt = 0; nt < 4; ++nt) {
                float val = s[mt][nt][r] * kScale + brow[nt * 16];
                sv[nt] = val;
                mx = fmaxf(mx, val);
            }
            for (int m2 = 1; m2 <= 8; m2 <<= 1) mx = fmaxf(mx, __shfl_xor(mx, m2, 64));
            float sum = 0.f;
            for (int nt = 0; nt < 4; ++nt) {
                float p = __expf(sv[nt] - mx);
                sum += p;
                int jj = nt * 16 + c;
                *(bf16*)(pbase + i * 128 + ((jj * 2) ^ ((i & 7) << 4))) = (bf16)p;
            }
            for (int m2 = 1; m2 <= 8; m2 <<= 1) sum += __shfl_xor(sum, m2, 64);
            lsum[mt][r] = sum;
        }
    }

    // ---- stage 4: O = P @ V  (K=64 over key tokens) ----
    f32x4 o[4][2];
    for (int mt = 0; mt < 4; ++mt) for (int nt = 0; nt < 2; ++nt) o[mt][nt] = fz;
    for (int ks = 0; ks < 2; ++ks) {
        bf16x8 ap[4];
        for (int mt = 0; mt < 4; ++mt) {
            int row = mt * 16 + c;
            ap[mt] = *(const bf16x8*)(pbase + row * 128 + ((ks * 64 + g * 16) ^ ((row & 7) << 4)));
        }
        for (int nt = 0; nt < 2; ++nt) {
            int dd = nt * 16 + c;
            bf16x8 bv = *(const bf16x8*)(vtbase + dd * 128 + ((ks * 64 + g * 16) ^ ((dd & 7) << 4)));
            for (int mt = 0; mt < 4; ++mt) o[mt][nt] = mfma16(ap[mt], bv, o[mt][nt]);
        }
    }
    // normalize rows, store head's 32 cols of ao into hb (rows 49..63 stay zero)
    for (int mt = 0; mt < 4; ++mt)
        for (int r = 0; r < 4; ++r) {
            int i = mt * 16 + g * 4 + r;
            if (i < NTOK) {
                float inv = 1.0f / lsum[mt][r];
                for (int nt = 0; nt < 2; ++nt) {
                    int col = head * 32 + nt * 16 + c;
                    *(bf16*)((char*)hb + i * 256 + ((col * 2) ^ ((i & 7) << 4))) = (bf16)(o[mt][nt][r] * inv);
                }
            }
        }
    __syncthreads();

    // ---- stage 5: proj (each wave: 32 output cols) + residual scatter ----
    f32x4 pj[4][2];
    for (int mt = 0; mt < 4; ++mt) for (int nt = 0; nt < 2; ++nt) pj[mt][nt] = fz;
    for (int ks = 0; ks < 4; ++ks) {
        bf16x8 af[4];
        int koff = ks * 64 + g * 16;
        for (int mt = 0; mt < 4; ++mt) {
            int row = mt * 16 + c;
            af[mt] = *(const bf16x8*)((char*)hb + row * 256 + (koff ^ ((row & 7) << 4)));
        }
        for (int nt = 0; nt < 2; ++nt) {
            int colw = wave * 32 + nt * 16 + c;
            bf16x8 bp = *(const bf16x8*)(projw + (size_t)colw * 128 + ks * 32 + g * 8);
            for (int mt = 0; mt < 4; ++mt) pj[mt][nt] = mfma16(af[mt], bp, pj[mt][nt]);
        }
    }
    float pb0 = proj_b[wave * 32 + c];
    float pb1 = proj_b[wave * 32 + 16 + c];
    for (int mt = 0; mt < 4; ++mt)
        for (int r = 0; r < 4; ++r) {
            int i = mt * 16 + g * 4 + r;
            if (i < NTOK) {
                int rr = i / 7, cc = i - rr * 7;
                int row = wi * 7 + rr + SHIFT3;  if (row >= HW) row -= HW;
                int col = wj * 7 + cc + SHIFT3;  if (col >= HW) col -= HW;
                size_t base = ((size_t)(b * 3136 + row * 56 + col)) << 7;
                int c0 = wave * 32 + c;
                yout[base + c0]      = x[base + c0]      + pj[mt][0][r] + pb0;
                yout[base + c0 + 16] = x[base + c0 + 16] + pj[mt][1][r] + pb1;
            }
        }
}

// ---------------- MLP: LN2 -> fc1+gelu -> fc2 -> +residual (in-place) ----------------

__global__ __launch_bounds__(256, 2) void mlp_kernel(
    const float* __restrict__ n2w, const float* __restrict__ n2b,
    const bf16*  __restrict__ fc1w, const float* __restrict__ fc1_b,
    const bf16*  __restrict__ fc2w, const float* __restrict__ fc2_b,
    float* __restrict__ y)
{
    __shared__ __align__(16) char smem[40960];
    bf16* const h2    = (bf16*)smem;     // [32][128] bf16, 256B rows
    char* const abase = smem + 8192;     // [32][512] bf16, 1024B rows

    const int tid  = threadIdx.x;
    const int wave = tid >> 6;
    const int lane = tid & 63;
    const int g = lane >> 4;
    const int c = lane & 15;
    const size_t t0 = (size_t)blockIdx.x * 32;

    // LN2
    {
        const int slot = tid >> 5, l32 = tid & 31;
        for (int it = 0; it < 4; ++it) {
            int t = slot + (it << 3);                   // 0..31
            const float* src = y + ((t0 + t) << 7) + (l32 << 2);
            float4 v = *(const float4*)src;
            float s  = v.x + v.y + v.z + v.w;
            float s2 = v.x * v.x + v.y * v.y + v.z * v.z + v.w * v.w;
            for (int m = 1; m <= 16; m <<= 1) {
                s  += __shfl_xor(s,  m, 64);
                s2 += __shfl_xor(s2, m, 64);
            }
            float mean = s * (1.0f / 128.0f);
            float var  = s2 * (1.0f / 128.0f) - mean * mean;
            float rs   = rsqrtf(var + 1e-5f);
            float4 wv = *(const float4*)(n2w + (l32 << 2));
            float4 bv = *(const float4*)(n2b + (l32 << 2));
            bf16x4 outv;
            outv[0] = (bf16)((v.x - mean) * rs * wv.x + bv.x);
            outv[1] = (bf16)((v.y - mean) * rs * wv.y + bv.y);
            outv[2] = (bf16)((v.z - mean) * rs * wv.z + bv.z);
            outv[3] = (bf16)((v.w - mean) * rs * wv.w + bv.w);
            int off = (l32 << 3) ^ ((t & 7) << 4);
            *(bf16x4*)((char*)h2 + t * 256 + off) = outv;
        }
    }
    __syncthreads();

    // fc1: each wave computes 128 hidden cols
    f32x4 fz = {0.f, 0.f, 0.f, 0.f};
    f32x4 a1[2][8];
    for (int mt = 0; mt < 2; ++mt) for (int nt = 0; nt < 8; ++nt) a1[mt][nt] = fz;
    for (int ks = 0; ks < 4; ++ks) {
        bf16x8 af[2];
        int koff = ks * 64 + g * 16;
        for (int mt = 0; mt < 2; ++mt) {
            int row = mt * 16 + c;
            af[mt] = *(const bf16x8*)((char*)h2 + row * 256 + (koff ^ ((row & 7) << 4)));
        }
        for (int nt = 0; nt < 8; ++nt) {
            int col = wave * 128 + nt * 16 + c;
            bf16x8 bw = *(const bf16x8*)(fc1w + (size_t)col * 128 + ks * 32 + g * 8);
            for (int mt = 0; mt < 2; ++mt) a1[mt][nt] = mfma16(af[mt], bw, a1[mt][nt]);
        }
    }
    for (int nt = 0; nt < 8; ++nt) {
        int col = wave * 128 + nt * 16 + c;
        float fb = fc1_b[col];
        for (int mt = 0; mt < 2; ++mt)
            for (int r = 0; r < 4; ++r) {
                int row = mt * 16 + g * 4 + r;
                float xv = a1[mt][nt][r] + fb;
                float ge = 0.5f * xv * (1.0f + erff(xv * 0.70710678118654752f));  // exact gelu
                *(bf16*)(abase + row * 1024 + ((col * 2) ^ ((row & 7) << 4))) = (bf16)ge;
            }
    }
    __syncthreads();

    // fc2: each wave computes 32 output cols; K = 512
    f32x4 a2[2][2];
    for (int mt = 0; mt < 2; ++mt) for (int nt = 0; nt < 2; ++nt) a2[mt][nt] = fz;
    for (int ks = 0; ks < 16; ++ks) {
        bf16x8 af[2];
        int koff = ks * 64 + g * 16;
        for (int mt = 0; mt < 2; ++mt) {
            int row = mt * 16 + c;
            af[mt] = *(const bf16x8*)(abase + row * 1024 + (koff ^ ((row & 7) << 4)));
        }
        for (int nt = 0; nt < 2; ++nt) {
            int col = wave * 32 + nt * 16 + c;
            bf16x8 bw = *(const bf16x8*)(fc2w + (size_t)col * 512 + ks * 32 + g * 8);
            for (int mt = 0; mt < 2; ++mt) a2[mt][nt] = mfma16(af[mt], bw, a2[mt][nt]);
        }
    }
    for (int nt = 0; nt < 2; ++nt) {
        int col = wave * 32 + nt * 16 + c;
        float fb = fc2_b[col];
        for (int mt = 0; mt < 2; ++mt)
            for (int r = 0; r < 4; ++r) {
                int row = mt * 16 + g * 4 + r;
                size_t idx = ((t0 + row) << 7) + col;
                y[idx] = y[idx] + a2[mt][nt][r] + fb;   // residual, in place
            }
    }
}

// ---------------- launch ----------------

extern "C" void kernel_launch(void* const* d_in, const int* in_sizes, int n_in,
                              void* d_out, int out_size, void* d_ws, size_t ws_size,
                              hipStream_t stream) {
    const float* x        = (const float*)d_in[0];
    // d_in[1] attn_mask: unused by the reference (faithful)
    const float* n1w      = (const float*)d_in[2];
    const float* n1b      = (const float*)d_in[3];
    const float* qkv_w    = (const float*)d_in[4];
    const float* qkv_b    = (const float*)d_in[5];
    const float* rel_tab  = (const float*)d_in[6];
    const int*   rel_idx  = (const int*)d_in[7];
    const float* proj_w   = (const float*)d_in[8];
    const float* proj_b   = (const float*)d_in[9];
    const float* n2w      = (const float*)d_in[10];
    const float* n2b      = (const float*)d_in[11];
    const float* fc1_w    = (const float*)d_in[12];
    const float* fc1_b    = (const float*)d_in[13];
    const float* fc2_w    = (const float*)d_in[14];
    const float* fc2_b    = (const float*)d_in[15];

    float* yout = (float*)d_out;
    char*  ws   = (char*)d_ws;
    float* biasbuf = (float*)(ws + WS_BIAS);
    bf16*  qkvw  = (bf16*)(ws + WS_QKVW);
    bf16*  projw = (bf16*)(ws + WS_PROJW);
    bf16*  fc1w  = (bf16*)(ws + WS_FC1W);
    bf16*  fc2w  = (bf16*)(ws + WS_FC2W);

    bias_kernel<<<dim3(49), dim3(256), 0, stream>>>(rel_tab, rel_idx, biasbuf);
    wcvt_kernel<<<dim3(768), dim3(256), 0, stream>>>(qkv_w, proj_w, fc1_w, fc2_w,
                                                     qkvw, projw, fc1w, fc2w);
    attn_kernel<<<dim3(2048), dim3(256), 0, stream>>>(x, n1w, n1b, qkvw, qkv_b,
                                                      projw, proj_b, biasbuf, yout);
    mlp_kernel<<<dim3(3136), dim3(256), 0, stream>>>(n2w, n2b, fc1w, fc1_b,
                                                     fc2w, fc2_b, yout);
}

// Round 3
// 303.083 us; speedup vs baseline: 1.0390x; 1.0390x over previous
//
#include <hip/hip_runtime.h>

typedef __bf16 bf16;
typedef __bf16 bf16x4 __attribute__((ext_vector_type(4)));
typedef __bf16 bf16x8 __attribute__((ext_vector_type(8)));
typedef float f32x4 __attribute__((ext_vector_type(4)));

#define NTOK 49
#define HW 56
#define SHIFT3 3
constexpr float kScale = 0.17677669529663687f;  // 32^-0.5

// ws layout (bytes, 16B aligned)
#define WS_BIAS  0        // f32 [4*49*64]   = 50176 B
#define WS_QKVW  50176    // bf16[49152] packed [ks4][row384][g4][8]
#define WS_PROJW 148480   // bf16[16384] packed [ks4][col128][g4][8]
#define WS_FC1W  181248   // bf16[65536] packed [ks4][col512][g4][8]
#define WS_FC2W  312320   // bf16[65536] packed [ks16][col128][g4][8]

static __device__ __forceinline__ f32x4 mfma16(bf16x8 a, bf16x8 b, f32x4 c) {
    return __builtin_amdgcn_mfma_f32_16x16x32_bf16(a, b, c, 0, 0, 0);
}

static __device__ __forceinline__ float gelu_f(float x) {
    // tanh-form gelu via sigmoid: 0.5x(1+tanh(u)) = x * sigmoid(2u)
    float x2 = x * x;
    float u2 = x * (1.5957691216f + 0.0713548162f * x2);   // 2u
    return x / (1.0f + __expf(-u2));
}

// ---------------- setup kernels ----------------

__global__ void bias_kernel(const float* __restrict__ rel_table,
                            const int* __restrict__ rel_index,
                            float* __restrict__ biasbuf) {
    int idx = blockIdx.x * 256 + threadIdx.x;     // over 4*49*64 = 12544
    if (idx >= 4 * NTOK * 64) return;
    int j = idx & 63;
    int rest = idx >> 6;
    int i = rest % NTOK;
    int h = rest / NTOK;
    float v = -1e30f;                             // masks j >= 49 (K padding)
    if (j < NTOK) v = rel_table[rel_index[i * NTOK + j] * 4 + h];
    biasbuf[idx] = v;
}

// pack weights for fully-coalesced B-fragment loads: out[((ks*R+row)*4+g)*8+e] = w[row][ks*32+g*8+e]
__global__ void wcvt_kernel(const float* __restrict__ qkv_w, const float* __restrict__ proj_w,
                            const float* __restrict__ fc1_w, const float* __restrict__ fc2_w,
                            bf16* __restrict__ qkvwp, bf16* __restrict__ projwp,
                            bf16* __restrict__ fc1wp, bf16* __restrict__ fc2wp) {
    int idx = blockIdx.x * 256 + threadIdx.x;     // 768*256 = 196608 exactly
    if (idx < 49152) {
        int o = idx, e = o & 7, t = o >> 3, g = t & 3; t >>= 2;
        int row = t % 384, ks = t / 384;
        qkvwp[o] = (bf16)qkv_w[row * 128 + ks * 32 + g * 8 + e];
    } else if (idx < 65536) {
        int o = idx - 49152, e = o & 7, t = o >> 3, g = t & 3; t >>= 2;
        int row = t % 128, ks = t / 128;
        projwp[o] = (bf16)proj_w[row * 128 + ks * 32 + g * 8 + e];
    } else if (idx < 131072) {
        int o = idx - 65536, e = o & 7, t = o >> 3, g = t & 3; t >>= 2;
        int row = t % 512, ks = t / 512;
        fc1wp[o] = (bf16)fc1_w[row * 128 + ks * 32 + g * 8 + e];
    } else {
        int o = idx - 131072, e = o & 7, t = o >> 3, g = t & 3; t >>= 2;
        int row = t % 128, ks = t / 128;
        fc2wp[o] = (bf16)fc2_w[row * 512 + ks * 32 + g * 8 + e];
    }
}

// ---------------- fused attention (per-window) ----------------
// block = one 7x7 window; 4 waves = 4 heads. LDS 64KB -> 2 blocks/CU.

__global__ __launch_bounds__(256, 2) void attn_kernel(
    const float* __restrict__ x,
    const float* __restrict__ n1w, const float* __restrict__ n1b,
    const bf16*  __restrict__ qkvwp, const float* __restrict__ qkv_b,
    const bf16*  __restrict__ projwp, const float* __restrict__ proj_b,
    const float* __restrict__ biasbuf,
    float* __restrict__ yout)
{
    __shared__ __align__(16) char smem[65536];
    bf16* const hb = (bf16*)smem;                       // h / ao: [64][128] bf16, 256B rows

    const int tid  = threadIdx.x;
    const int wave = tid >> 6;
    const int lane = tid & 63;
    const int g = lane >> 4;     // 0..3 (k-chunk group)
    const int c = lane & 15;     // 0..15

    char* const qbase  = smem + 16384 + wave * 8192;    // q [64][32] 64B rows
    char* const kbase  = qbase + 4096;                  // k [64][32]
    char* const pbase  = qbase;                         // P [64][64] 128B rows (overlays q+k)
    char* const vtbase = smem + 49152 + wave * 4096;    // vT [32][64] 128B rows

    const int w  = blockIdx.x;
    const int b  = w >> 6;
    const int wi = (w >> 3) & 7;
    const int wj = w & 7;
    const int head = wave;

    // ---- stage 0: LN1 + shifted-window gather -> hb (rows 49..63 zeroed) ----
    {
        const int slot = tid >> 5, l32 = tid & 31;
        for (int it = 0; it < 8; ++it) {
            int t  = slot + (it << 3);                  // 0..63
            int tt = t < NTOK ? t : NTOK - 1;
            int r  = tt / 7, cc = tt - r * 7;
            int row = wi * 7 + r + SHIFT3;  if (row >= HW) row -= HW;
            int col = wj * 7 + cc + SHIFT3; if (col >= HW) col -= HW;
            const float* src = x + (((size_t)(b * 3136 + row * 56 + col)) << 7) + (l32 << 2);
            float4 v = *(const float4*)src;
            float s  = v.x + v.y + v.z + v.w;
            float s2 = v.x * v.x + v.y * v.y + v.z * v.z + v.w * v.w;
            for (int m = 1; m <= 16; m <<= 1) {         // reduce within 32-lane group
                s  += __shfl_xor(s,  m, 64);
                s2 += __shfl_xor(s2, m, 64);
            }
            float mean = s * (1.0f / 128.0f);
            float var  = s2 * (1.0f / 128.0f) - mean * mean;
            float rs   = rsqrtf(var + 1e-5f);
            float4 wv = *(const float4*)(n1w + (l32 << 2));
            float4 bv = *(const float4*)(n1b + (l32 << 2));
            bf16x4 outv;
            if (t < NTOK) {
                outv[0] = (bf16)((v.x - mean) * rs * wv.x + bv.x);
                outv[1] = (bf16)((v.y - mean) * rs * wv.y + bv.y);
                outv[2] = (bf16)((v.z - mean) * rs * wv.z + bv.z);
                outv[3] = (bf16)((v.w - mean) * rs * wv.w + bv.w);
            } else {
                outv[0] = (bf16)0.0f; outv[1] = (bf16)0.0f;
                outv[2] = (bf16)0.0f; outv[3] = (bf16)0.0f;
            }
            int off = (l32 << 3) ^ ((t & 7) << 4);      // swizzled byte off in 256B row
            *(bf16x4*)((char*)hb + t * 256 + off) = outv;
        }
    }
    __syncthreads();

    // ---- stage 1: qkv = h @ Wqkv^T (per head), MFMA 16x16x32 ----
    f32x4 fz = {0.f, 0.f, 0.f, 0.f};
    f32x4 qa[4][2], ka[4][2], va[4][2];
    for (int mt = 0; mt < 4; ++mt)
        for (int nt = 0; nt < 2; ++nt) { qa[mt][nt] = fz; ka[mt][nt] = fz; va[mt][nt] = fz; }

    for (int ks = 0; ks < 4; ++ks) {
        bf16x8 af[4];
        const int koff = ks * 64 + g * 16;              // byte offset within 256B row
        for (int mt = 0; mt < 4; ++mt) {
            int row = mt * 16 + c;
            af[mt] = *(const bf16x8*)((char*)hb + row * 256 + (koff ^ ((row & 7) << 4)));
        }
        for (int nt = 0; nt < 2; ++nt) {
            int jb = head * 32 + nt * 16 + c;           // out-channel within Q block
            bf16x8 bq = *(const bf16x8*)(qkvwp + (((ks * 384 + jb) * 4 + g) << 3));
            bf16x8 bk = *(const bf16x8*)(qkvwp + (((ks * 384 + 128 + jb) * 4 + g) << 3));
            bf16x8 bv = *(const bf16x8*)(qkvwp + (((ks * 384 + 256 + jb) * 4 + g) << 3));
            for (int mt = 0; mt < 4; ++mt) {
                qa[mt][nt] = mfma16(af[mt], bq, qa[mt][nt]);
                ka[mt][nt] = mfma16(af[mt], bk, ka[mt][nt]);
                va[mt][nt] = mfma16(af[mt], bv, va[mt][nt]);
            }
        }
    }
    // store q,k (row-major [64][32]) and v transposed (vT [32][64]); +qkv bias
    for (int nt = 0; nt < 2; ++nt) {
        int dl = nt * 16 + c;                           // 0..31
        float bq = qkv_b[head * 32 + dl];
        float bk = qkv_b[128 + head * 32 + dl];
        float bv = qkv_b[256 + head * 32 + dl];
        for (int mt = 0; mt < 4; ++mt)
            for (int r = 0; r < 4; ++r) {
                int tok = mt * 16 + g * 4 + r;          // C-frag row
                *(bf16*)(qbase + tok * 64 + ((dl * 2) ^ ((tok & 3) << 4))) = (bf16)(qa[mt][nt][r] + bq);
                *(bf16*)(kbase + tok * 64 + ((dl * 2) ^ ((tok & 3) << 4))) = (bf16)(ka[mt][nt][r] + bk);
                *(bf16*)(vtbase + dl * 128 + ((tok * 2) ^ ((dl & 7) << 4))) = (bf16)(va[mt][nt][r] + bv);
            }
    }
    __syncthreads();   // all h reads done (hb reused for ao below)

    // ---- stage 2: S = q k^T (K=32, one MFMA step) ----
    f32x4 s[4][4];
    for (int mt = 0; mt < 4; ++mt) for (int nt = 0; nt < 4; ++nt) s[mt][nt] = fz;
    {
        bf16x8 aq[4];
        for (int mt = 0; mt < 4; ++mt) {
            int row = mt * 16 + c;
            aq[mt] = *(const bf16x8*)(qbase + row * 64 + ((g * 16) ^ ((row & 3) << 4)));
        }
        for (int nt = 0; nt < 4; ++nt) {
            int row = nt * 16 + c;
            bf16x8 bk = *(const bf16x8*)(kbase + row * 64 + ((g * 16) ^ ((row & 3) << 4)));
            for (int mt = 0; mt < 4; ++mt) s[mt][nt] = mfma16(aq[mt], bk, s[mt][nt]);
        }
    }

    // ---- stage 3: softmax rows (bias includes -1e30 mask at j>=49) ----
    const float* bbase = biasbuf + head * (NTOK * 64);
    float lsum[4][4];
    for (int mt = 0; mt < 4; ++mt) {
        for (int r = 0; r < 4; ++r) {
            int i  = mt * 16 + g * 4 + r;
            int im = i < NTOK ? i : NTOK - 1;
            const float* brow = bbase + im * 64 + c;
            float sv[4];
            float mx = -3e38f;
            for (int nt = 0; nt < 4; ++nt) {
                float val = s[mt][nt][r] * kScale + brow[nt * 16];
                sv[nt] = val;
                mx = fmaxf(mx, val);
            }
            for (int m2 = 1; m2 <= 8; m2 <<= 1) mx = fmaxf(mx, __shfl_xor(mx, m2, 64));
            float sum = 0.f;
            for (int nt = 0; nt < 4; ++nt) {
                float p = __expf(sv[nt] - mx);
                sum += p;
                int jj = nt * 16 + c;
                *(bf16*)(pbase + i * 128 + ((jj * 2) ^ ((i & 7) << 4))) = (bf16)p;
            }
            for (int m2 = 1; m2 <= 8; m2 <<= 1) sum += __shfl_xor(sum, m2, 64);
            lsum[mt][r] = sum;
        }
    }

    // ---- stage 4: O = P @ V  (K=64 over key tokens) ----
    f32x4 o[4][2];
    for (int mt = 0; mt < 4; ++mt) for (int nt = 0; nt < 2; ++nt) o[mt][nt] = fz;
    for (int ks = 0; ks < 2; ++ks) {
        bf16x8 ap[4];
        for (int mt = 0; mt < 4; ++mt) {
            int row = mt * 16 + c;
            ap[mt] = *(const bf16x8*)(pbase + row * 128 + ((ks * 64 + g * 16) ^ ((row & 7) << 4)));
        }
        for (int nt = 0; nt < 2; ++nt) {
            int dd = nt * 16 + c;
            bf16x8 bv = *(const bf16x8*)(vtbase + dd * 128 + ((ks * 64 + g * 16) ^ ((dd & 7) << 4)));
            for (int mt = 0; mt < 4; ++mt) o[mt][nt] = mfma16(ap[mt], bv, o[mt][nt]);
        }
    }
    // normalize rows, store head's 32 cols of ao into hb (rows 49..63 stay zero)
    for (int mt = 0; mt < 4; ++mt)
        for (int r = 0; r < 4; ++r) {
            int i = mt * 16 + g * 4 + r;
            if (i < NTOK) {
                float inv = 1.0f / lsum[mt][r];
                for (int nt = 0; nt < 2; ++nt) {
                    int col = head * 32 + nt * 16 + c;
                    *(bf16*)((char*)hb + i * 256 + ((col * 2) ^ ((i & 7) << 4))) = (bf16)(o[mt][nt][r] * inv);
                }
            }
        }
    __syncthreads();

    // ---- stage 5: proj (each wave: 32 output cols) + residual scatter ----
    f32x4 pj[4][2];
    for (int mt = 0; mt < 4; ++mt) for (int nt = 0; nt < 2; ++nt) pj[mt][nt] = fz;
    for (int ks = 0; ks < 4; ++ks) {
        bf16x8 af[4];
        int koff = ks * 64 + g * 16;
        for (int mt = 0; mt < 4; ++mt) {
            int row = mt * 16 + c;
            af[mt] = *(const bf16x8*)((char*)hb + row * 256 + (koff ^ ((row & 7) << 4)));
        }
        for (int nt = 0; nt < 2; ++nt) {
            int colw = wave * 32 + nt * 16 + c;
            bf16x8 bp = *(const bf16x8*)(projwp + (((ks * 128 + colw) * 4 + g) << 3));
            for (int mt = 0; mt < 4; ++mt) pj[mt][nt] = mfma16(af[mt], bp, pj[mt][nt]);
        }
    }
    float pb0 = proj_b[wave * 32 + c];
    float pb1 = proj_b[wave * 32 + 16 + c];
    for (int mt = 0; mt < 4; ++mt)
        for (int r = 0; r < 4; ++r) {
            int i = mt * 16 + g * 4 + r;
            if (i < NTOK) {
                int rr = i / 7, cc = i - rr * 7;
                int row = wi * 7 + rr + SHIFT3;  if (row >= HW) row -= HW;
                int col = wj * 7 + cc + SHIFT3;  if (col >= HW) col -= HW;
                size_t base = ((size_t)(b * 3136 + row * 56 + col)) << 7;
                int c0 = wave * 32 + c;
                yout[base + c0]      = x[base + c0]      + pj[mt][0][r] + pb0;
                yout[base + c0 + 16] = x[base + c0 + 16] + pj[mt][1][r] + pb1;
            }
        }
}

// ---------------- MLP: LN2 -> fc1+gelu -> fc2 -> +residual (in-place) ----------------
// BM=64 tokens/block, 1568 blocks. LDS 80KB -> 2 blocks/CU.

__global__ __launch_bounds__(256, 2) void mlp_kernel(
    const float* __restrict__ n2w, const float* __restrict__ n2b,
    const bf16*  __restrict__ fc1wp, const float* __restrict__ fc1_b,
    const bf16*  __restrict__ fc2wp, const float* __restrict__ fc2_b,
    float* __restrict__ y)
{
    __shared__ __align__(16) char smem[81920];
    bf16* const h2    = (bf16*)smem;     // [64][128] bf16, 256B rows
    char* const abase = smem + 16384;    // [64][512] bf16, 1024B rows

    const int tid  = threadIdx.x;
    const int wave = tid >> 6;
    const int lane = tid & 63;
    const int g = lane >> 4;
    const int c = lane & 15;
    const size_t t0 = (size_t)blockIdx.x * 64;

    // LN2 over 64 tokens
    {
        const int slot = tid >> 5, l32 = tid & 31;
        for (int it = 0; it < 8; ++it) {
            int t = slot + (it << 3);                   // 0..63
            const float* src = y + ((t0 + t) << 7) + (l32 << 2);
            float4 v = *(const float4*)src;
            float s  = v.x + v.y + v.z + v.w;
            float s2 = v.x * v.x + v.y * v.y + v.z * v.z + v.w * v.w;
            for (int m = 1; m <= 16; m <<= 1) {
                s  += __shfl_xor(s,  m, 64);
                s2 += __shfl_xor(s2, m, 64);
            }
            float mean = s * (1.0f / 128.0f);
            float var  = s2 * (1.0f / 128.0f) - mean * mean;
            float rs   = rsqrtf(var + 1e-5f);
            float4 wv = *(const float4*)(n2w + (l32 << 2));
            float4 bv = *(const float4*)(n2b + (l32 << 2));
            bf16x4 outv;
            outv[0] = (bf16)((v.x - mean) * rs * wv.x + bv.x);
            outv[1] = (bf16)((v.y - mean) * rs * wv.y + bv.y);
            outv[2] = (bf16)((v.z - mean) * rs * wv.z + bv.z);
            outv[3] = (bf16)((v.w - mean) * rs * wv.w + bv.w);
            int off = (l32 << 3) ^ ((t & 7) << 4);
            *(bf16x4*)((char*)h2 + t * 256 + off) = outv;
        }
    }
    __syncthreads();

    // fc1: each wave computes 128 hidden cols for all 64 rows
    f32x4 fz = {0.f, 0.f, 0.f, 0.f};
    f32x4 a1[4][8];
    for (int mt = 0; mt < 4; ++mt) for (int nt = 0; nt < 8; ++nt) a1[mt][nt] = fz;
    for (int ks = 0; ks < 4; ++ks) {
        bf16x8 af[4];
        int koff = ks * 64 + g * 16;
        for (int mt = 0; mt < 4; ++mt) {
            int row = mt * 16 + c;
            af[mt] = *(const bf16x8*)((char*)h2 + row * 256 + (koff ^ ((row & 7) << 4)));
        }
        for (int nt = 0; nt < 8; ++nt) {
            int col = wave * 128 + nt * 16 + c;
            bf16x8 bw = *(const bf16x8*)(fc1wp + (((ks * 512 + col) * 4 + g) << 3));
            for (int mt = 0; mt < 4; ++mt) a1[mt][nt] = mfma16(af[mt], bw, a1[mt][nt]);
        }
    }
    for (int nt = 0; nt < 8; ++nt) {
        int col = wave * 128 + nt * 16 + c;
        float fb = fc1_b[col];
        for (int mt = 0; mt < 4; ++mt)
            for (int r = 0; r < 4; ++r) {
                int row = mt * 16 + g * 4 + r;
                float ge = gelu_f(a1[mt][nt][r] + fb);
                *(bf16*)(abase + row * 1024 + ((col * 2) ^ ((row & 7) << 4))) = (bf16)ge;
            }
    }
    __syncthreads();

    // fc2: each wave computes 32 output cols; K = 512
    f32x4 a2[4][2];
    for (int mt = 0; mt < 4; ++mt) for (int nt = 0; nt < 2; ++nt) a2[mt][nt] = fz;
    for (int ks = 0; ks < 16; ++ks) {
        bf16x8 af[4];
        int koff = ks * 64 + g * 16;
        for (int mt = 0; mt < 4; ++mt) {
            int row = mt * 16 + c;
            af[mt] = *(const bf16x8*)(abase + row * 1024 + (koff ^ ((row & 7) << 4)));
        }
        for (int nt = 0; nt < 2; ++nt) {
            int col = wave * 32 + nt * 16 + c;
            bf16x8 bw = *(const bf16x8*)(fc2wp + (((ks * 128 + col) * 4 + g) << 3));
            for (int mt = 0; mt < 2; ++mt) a2[mt][nt] = mfma16(af[mt], bw, a2[mt][nt]);
            for (int mt = 2; mt < 4; ++mt) a2[mt][nt] = mfma16(af[mt], bw, a2[mt][nt]);
        }
    }
    for (int nt = 0; nt < 2; ++nt) {
        int col = wave * 32 + nt * 16 + c;
        float fb = fc2_b[col];
        for (int mt = 0; mt < 4; ++mt)
            for (int r = 0; r < 4; ++r) {
                int row = mt * 16 + g * 4 + r;
                size_t idx = ((t0 + row) << 7) + col;
                y[idx] = y[idx] + a2[mt][nt][r] + fb;   // residual, in place
            }
    }
}

// ---------------- launch ----------------

extern "C" void kernel_launch(void* const* d_in, const int* in_sizes, int n_in,
                              void* d_out, int out_size, void* d_ws, size_t ws_size,
                              hipStream_t stream) {
    const float* x        = (const float*)d_in[0];
    // d_in[1] attn_mask: unused by the reference (faithful)
    const float* n1w      = (const float*)d_in[2];
    const float* n1b      = (const float*)d_in[3];
    const float* qkv_w    = (const float*)d_in[4];
    const float* qkv_b    = (const float*)d_in[5];
    const float* rel_tab  = (const float*)d_in[6];
    const int*   rel_idx  = (const int*)d_in[7];
    const float* proj_w   = (const float*)d_in[8];
    const float* proj_b   = (const float*)d_in[9];
    const float* n2w      = (const float*)d_in[10];
    const float* n2b      = (const float*)d_in[11];
    const float* fc1_w    = (const float*)d_in[12];
    const float* fc1_b    = (const float*)d_in[13];
    const float* fc2_w    = (const float*)d_in[14];
    const float* fc2_b    = (const float*)d_in[15];

    float* yout = (float*)d_out;
    char*  ws   = (char*)d_ws;
    float* biasbuf = (float*)(ws + WS_BIAS);
    bf16*  qkvwp = (bf16*)(ws + WS_QKVW);
    bf16*  projwp= (bf16*)(ws + WS_PROJW);
    bf16*  fc1wp = (bf16*)(ws + WS_FC1W);
    bf16*  fc2wp = (bf16*)(ws + WS_FC2W);

    bias_kernel<<<dim3(49), dim3(256), 0, stream>>>(rel_tab, rel_idx, biasbuf);
    wcvt_kernel<<<dim3(768), dim3(256), 0, stream>>>(qkv_w, proj_w, fc1_w, fc2_w,
                                                     qkvwp, projwp, fc1wp, fc2wp);
    attn_kernel<<<dim3(2048), dim3(256), 0, stream>>>(x, n1w, n1b, qkvwp, qkv_b,
                                                      projwp, proj_b, biasbuf, yout);
    mlp_kernel<<<dim3(1568), dim3(256), 0, stream>>>(n2w, n2b, fc1wp, fc1_b,
                                                     fc2wp, fc2_b, yout);
}

// Round 5
// 277.401 us; speedup vs baseline: 1.1352x; 1.0926x over previous
//
#include <hip/hip_runtime.h>

typedef __bf16 bf16;
typedef __bf16 bf16x4 __attribute__((ext_vector_type(4)));
typedef __bf16 bf16x8 __attribute__((ext_vector_type(8)));
typedef float f32x4 __attribute__((ext_vector_type(4)));

#define NTOK 49
#define HW 56
#define SHIFT3 3
constexpr float kScale = 0.17677669529663687f;  // 32^-0.5

// ws layout (bytes, 16B aligned)
#define WS_BIAS  0        // f32 [4*49*64]   = 50176 B
#define WS_QKVW  50176    // bf16[49152] packed [ks4][row384][g4][8]
#define WS_PROJW 148480   // bf16[16384] packed [ks4][col128][g4][8]
#define WS_FC1W  181248   // bf16[65536] packed [ks4][col512][g4][8]
#define WS_FC2W  312320   // bf16[65536] packed [ks16][col128][g4][8]

static __device__ __forceinline__ f32x4 mfma16(bf16x8 a, bf16x8 b, f32x4 c) {
    return __builtin_amdgcn_mfma_f32_16x16x32_bf16(a, b, c, 0, 0, 0);
}

static __device__ __forceinline__ float gelu_f(float x) {
    // tanh-form gelu via sigmoid: 0.5x(1+tanh(u)) = x * sigmoid(2u)
    float x2 = x * x;
    float u2 = x * (1.5957691216f + 0.0713548162f * x2);   // 2u
    return x / (1.0f + __expf(-u2));
}

// ---------------- setup kernels ----------------

__global__ void bias_kernel(const float* __restrict__ rel_table,
                            const int* __restrict__ rel_index,
                            float* __restrict__ biasbuf) {
    int idx = blockIdx.x * 256 + threadIdx.x;     // over 4*49*64 = 12544
    if (idx >= 4 * NTOK * 64) return;
    int j = idx & 63;
    int rest = idx >> 6;
    int i = rest % NTOK;
    int h = rest / NTOK;
    float v = -1e30f;                             // masks j >= 49 (K padding)
    if (j < NTOK) v = rel_table[rel_index[i * NTOK + j] * 4 + h];
    biasbuf[idx] = v;
}

// pack weights for fully-coalesced B-fragment loads: out[((ks*R+row)*4+g)*8+e] = w[row][ks*32+g*8+e]
__global__ void wcvt_kernel(const float* __restrict__ qkv_w, const float* __restrict__ proj_w,
                            const float* __restrict__ fc1_w, const float* __restrict__ fc2_w,
                            bf16* __restrict__ qkvwp, bf16* __restrict__ projwp,
                            bf16* __restrict__ fc1wp, bf16* __restrict__ fc2wp) {
    int idx = blockIdx.x * 256 + threadIdx.x;     // 768*256 = 196608 exactly
    if (idx < 49152) {
        int o = idx, e = o & 7, t = o >> 3, g = t & 3; t >>= 2;
        int row = t % 384, ks = t / 384;
        qkvwp[o] = (bf16)qkv_w[row * 128 + ks * 32 + g * 8 + e];
    } else if (idx < 65536) {
        int o = idx - 49152, e = o & 7, t = o >> 3, g = t & 3; t >>= 2;
        int row = t % 128, ks = t / 128;
        projwp[o] = (bf16)proj_w[row * 128 + ks * 32 + g * 8 + e];
    } else if (idx < 131072) {
        int o = idx - 65536, e = o & 7, t = o >> 3, g = t & 3; t >>= 2;
        int row = t % 512, ks = t / 512;
        fc1wp[o] = (bf16)fc1_w[row * 128 + ks * 32 + g * 8 + e];
    } else {
        int o = idx - 131072, e = o & 7, t = o >> 3, g = t & 3; t >>= 2;
        int row = t % 128, ks = t / 128;
        fc2wp[o] = (bf16)fc2_w[row * 512 + ks * 32 + g * 8 + e];
    }
}

// ---------------- fused attention (per-window) ----------------
// block = one 7x7 window; 4 waves = 4 heads. LDS 64KB -> 2 blocks/CU.

__global__ __launch_bounds__(256, 2) void attn_kernel(
    const float* __restrict__ x,
    const float* __restrict__ n1w, const float* __restrict__ n1b,
    const bf16*  __restrict__ qkvwp, const float* __restrict__ qkv_b,
    const bf16*  __restrict__ projwp, const float* __restrict__ proj_b,
    const float* __restrict__ biasbuf,
    float* __restrict__ yout)
{
    __shared__ __align__(16) char smem[65536];
    bf16* const hb = (bf16*)smem;                       // h / ao: [64][128] bf16, 256B rows

    const int tid  = threadIdx.x;
    const int wave = tid >> 6;
    const int lane = tid & 63;
    const int g = lane >> 4;     // 0..3 (k-chunk group)
    const int c = lane & 15;     // 0..15

    char* const qbase  = smem + 16384 + wave * 8192;    // q [64][32] 64B rows
    char* const kbase  = qbase + 4096;                  // k [64][32]
    char* const pbase  = qbase;                         // P [64][64] 128B rows (overlays q+k)
    char* const vtbase = smem + 49152 + wave * 4096;    // vT [32][64] 128B rows

    const int w  = blockIdx.x;
    const int b  = w >> 6;
    const int wi = (w >> 3) & 7;
    const int wj = w & 7;
    const int head = wave;

    // ---- stage 0: LN1 + shifted-window gather -> hb (rows 49..63 zeroed) ----
    {
        const int slot = tid >> 5, l32 = tid & 31;
        for (int it = 0; it < 8; ++it) {
            int t  = slot + (it << 3);                  // 0..63
            int tt = t < NTOK ? t : NTOK - 1;
            int r  = tt / 7, cc = tt - r * 7;
            int row = wi * 7 + r + SHIFT3;  if (row >= HW) row -= HW;
            int col = wj * 7 + cc + SHIFT3; if (col >= HW) col -= HW;
            const float* src = x + (((size_t)(b * 3136 + row * 56 + col)) << 7) + (l32 << 2);
            float4 v = *(const float4*)src;
            float s  = v.x + v.y + v.z + v.w;
            float s2 = v.x * v.x + v.y * v.y + v.z * v.z + v.w * v.w;
            for (int m = 1; m <= 16; m <<= 1) {         // reduce within 32-lane group
                s  += __shfl_xor(s,  m, 64);
                s2 += __shfl_xor(s2, m, 64);
            }
            float mean = s * (1.0f / 128.0f);
            float var  = s2 * (1.0f / 128.0f) - mean * mean;
            float rs   = rsqrtf(var + 1e-5f);
            float4 wv = *(const float4*)(n1w + (l32 << 2));
            float4 bv = *(const float4*)(n1b + (l32 << 2));
            bf16x4 outv;
            if (t < NTOK) {
                outv[0] = (bf16)((v.x - mean) * rs * wv.x + bv.x);
                outv[1] = (bf16)((v.y - mean) * rs * wv.y + bv.y);
                outv[2] = (bf16)((v.z - mean) * rs * wv.z + bv.z);
                outv[3] = (bf16)((v.w - mean) * rs * wv.w + bv.w);
            } else {
                outv[0] = (bf16)0.0f; outv[1] = (bf16)0.0f;
                outv[2] = (bf16)0.0f; outv[3] = (bf16)0.0f;
            }
            int off = (l32 << 3) ^ ((t & 7) << 4);      // swizzled byte off in 256B row
            *(bf16x4*)((char*)hb + t * 256 + off) = outv;
        }
    }
    __syncthreads();

    // ---- stage 1: qkv = h @ Wqkv^T (per head), MFMA 16x16x32 ----
    // Split by nt (output 16-col group) to keep live accumulators at 48 f32
    // (spill fix: qa/ka/va[4][2]=96 floats was spilling to scratch).
    f32x4 fz = {0.f, 0.f, 0.f, 0.f};
    #pragma unroll 1
    for (int nt = 0; nt < 2; ++nt) {
        f32x4 qa[4], ka[4], va[4];
        #pragma unroll
        for (int mt = 0; mt < 4; ++mt) { qa[mt] = fz; ka[mt] = fz; va[mt] = fz; }

        #pragma unroll
        for (int ks = 0; ks < 4; ++ks) {
            bf16x8 af[4];
            const int koff = ks * 64 + g * 16;          // byte offset within 256B row
            #pragma unroll
            for (int mt = 0; mt < 4; ++mt) {
                int row = mt * 16 + c;
                af[mt] = *(const bf16x8*)((char*)hb + row * 256 + (koff ^ ((row & 7) << 4)));
            }
            int jb = head * 32 + nt * 16 + c;           // out-channel within Q block
            bf16x8 bq = *(const bf16x8*)(qkvwp + (((ks * 384 + jb) * 4 + g) << 3));
            bf16x8 bk = *(const bf16x8*)(qkvwp + (((ks * 384 + 128 + jb) * 4 + g) << 3));
            bf16x8 bv = *(const bf16x8*)(qkvwp + (((ks * 384 + 256 + jb) * 4 + g) << 3));
            #pragma unroll
            for (int mt = 0; mt < 4; ++mt) {
                qa[mt] = mfma16(af[mt], bq, qa[mt]);
                ka[mt] = mfma16(af[mt], bk, ka[mt]);
                va[mt] = mfma16(af[mt], bv, va[mt]);
            }
        }
        // store q,k (row-major [64][32]) and v transposed (vT [32][64]); +qkv bias
        int dl = nt * 16 + c;                           // 0..31
        float bqs = qkv_b[head * 32 + dl];
        float bks = qkv_b[128 + head * 32 + dl];
        float bvs = qkv_b[256 + head * 32 + dl];
        #pragma unroll
        for (int mt = 0; mt < 4; ++mt)
            #pragma unroll
            for (int r = 0; r < 4; ++r) {
                int tok = mt * 16 + g * 4 + r;          // C-frag row
                *(bf16*)(qbase + tok * 64 + ((dl * 2) ^ ((tok & 3) << 4))) = (bf16)(qa[mt][r] + bqs);
                *(bf16*)(kbase + tok * 64 + ((dl * 2) ^ ((tok & 3) << 4))) = (bf16)(ka[mt][r] + bks);
                *(bf16*)(vtbase + dl * 128 + ((tok * 2) ^ ((dl & 7) << 4))) = (bf16)(va[mt][r] + bvs);
            }
    }
    __syncthreads();   // all h reads done (hb reused for ao below)

    // ---- stage 2: S = q k^T (K=32, one MFMA step) ----
    f32x4 s[4][4];
    for (int mt = 0; mt < 4; ++mt) for (int nt = 0; nt < 4; ++nt) s[mt][nt] = fz;
    {
        bf16x8 aq[4];
        #pragma unroll
        for (int mt = 0; mt < 4; ++mt) {
            int row = mt * 16 + c;
            aq[mt] = *(const bf16x8*)(qbase + row * 64 + ((g * 16) ^ ((row & 3) << 4)));
        }
        #pragma unroll
        for (int nt = 0; nt < 4; ++nt) {
            int row = nt * 16 + c;
            bf16x8 bk = *(const bf16x8*)(kbase + row * 64 + ((g * 16) ^ ((row & 3) << 4)));
            #pragma unroll
            for (int mt = 0; mt < 4; ++mt) s[mt][nt] = mfma16(aq[mt], bk, s[mt][nt]);
        }
    }

    // ---- stage 3: softmax rows (bias includes -1e30 mask at j>=49) ----
    const float* bbase = biasbuf + head * (NTOK * 64);
    float lsum[4][4];
    for (int mt = 0; mt < 4; ++mt) {
        for (int r = 0; r < 4; ++r) {
            int i  = mt * 16 + g * 4 + r;
            int im = i < NTOK ? i : NTOK - 1;
            const float* brow = bbase + im * 64 + c;
            float sv[4];
            float mx = -3e38f;
            for (int nt = 0; nt < 4; ++nt) {
                float val = s[mt][nt][r] * kScale + brow[nt * 16];
                sv[nt] = val;
                mx = fmaxf(mx, val);
            }
            for (int m2 = 1; m2 <= 8; m2 <<= 1) mx = fmaxf(mx, __shfl_xor(mx, m2, 64));
            float sum = 0.f;
            for (int nt = 0; nt < 4; ++nt) {
                float p = __expf(sv[nt] - mx);
                sum += p;
                int jj = nt * 16 + c;
                *(bf16*)(pbase + i * 128 + ((jj * 2) ^ ((i & 7) << 4))) = (bf16)p;
            }
            for (int m2 = 1; m2 <= 8; m2 <<= 1) sum += __shfl_xor(sum, m2, 64);
            lsum[mt][r] = sum;
        }
    }

    // ---- stage 4: O = P @ V  (K=64 over key tokens) ----
    f32x4 o[4][2];
    for (int mt = 0; mt < 4; ++mt) for (int nt = 0; nt < 2; ++nt) o[mt][nt] = fz;
    #pragma unroll
    for (int ks = 0; ks < 2; ++ks) {
        bf16x8 ap[4];
        #pragma unroll
        for (int mt = 0; mt < 4; ++mt) {
            int row = mt * 16 + c;
            ap[mt] = *(const bf16x8*)(pbase + row * 128 + ((ks * 64 + g * 16) ^ ((row & 7) << 4)));
        }
        #pragma unroll
        for (int nt = 0; nt < 2; ++nt) {
            int dd = nt * 16 + c;
            bf16x8 bv = *(const bf16x8*)(vtbase + dd * 128 + ((ks * 64 + g * 16) ^ ((dd & 7) << 4)));
            #pragma unroll
            for (int mt = 0; mt < 4; ++mt) o[mt][nt] = mfma16(ap[mt], bv, o[mt][nt]);
        }
    }
    // normalize rows, store head's 32 cols of ao into hb (rows 49..63 stay zero)
    for (int mt = 0; mt < 4; ++mt)
        for (int r = 0; r < 4; ++r) {
            int i = mt * 16 + g * 4 + r;
            if (i < NTOK) {
                float inv = 1.0f / lsum[mt][r];
                for (int nt = 0; nt < 2; ++nt) {
                    int col = head * 32 + nt * 16 + c;
                    *(bf16*)((char*)hb + i * 256 + ((col * 2) ^ ((i & 7) << 4))) = (bf16)(o[mt][nt][r] * inv);
                }
            }
        }
    __syncthreads();

    // ---- stage 5: proj (each wave: 32 output cols) + residual scatter ----
    f32x4 pj[4][2];
    for (int mt = 0; mt < 4; ++mt) for (int nt = 0; nt < 2; ++nt) pj[mt][nt] = fz;
    #pragma unroll
    for (int ks = 0; ks < 4; ++ks) {
        bf16x8 af[4];
        int koff = ks * 64 + g * 16;
        #pragma unroll
        for (int mt = 0; mt < 4; ++mt) {
            int row = mt * 16 + c;
            af[mt] = *(const bf16x8*)((char*)hb + row * 256 + (koff ^ ((row & 7) << 4)));
        }
        #pragma unroll
        for (int nt = 0; nt < 2; ++nt) {
            int colw = wave * 32 + nt * 16 + c;
            bf16x8 bp = *(const bf16x8*)(projwp + (((ks * 128 + colw) * 4 + g) << 3));
            #pragma unroll
            for (int mt = 0; mt < 4; ++mt) pj[mt][nt] = mfma16(af[mt], bp, pj[mt][nt]);
        }
    }
    float pb0 = proj_b[wave * 32 + c];
    float pb1 = proj_b[wave * 32 + 16 + c];
    for (int mt = 0; mt < 4; ++mt)
        for (int r = 0; r < 4; ++r) {
            int i = mt * 16 + g * 4 + r;
            if (i < NTOK) {
                int rr = i / 7, cc = i - rr * 7;
                int row = wi * 7 + rr + SHIFT3;  if (row >= HW) row -= HW;
                int col = wj * 7 + cc + SHIFT3;  if (col >= HW) col -= HW;
                size_t base = ((size_t)(b * 3136 + row * 56 + col)) << 7;
                int c0 = wave * 32 + c;
                yout[base + c0]      = x[base + c0]      + pj[mt][0][r] + pb0;
                yout[base + c0 + 16] = x[base + c0 + 16] + pj[mt][1][r] + pb1;
            }
        }
}

// ---------------- MLP: LN2 -> fc1+gelu -> fc2 -> +residual (in-place) ----------------
// BM=64 tokens/block, 1568 blocks. LDS 80KB -> 2 blocks/CU.

__global__ __launch_bounds__(256, 2) void mlp_kernel(
    const float* __restrict__ n2w, const float* __restrict__ n2b,
    const bf16*  __restrict__ fc1wp, const float* __restrict__ fc1_b,
    const bf16*  __restrict__ fc2wp, const float* __restrict__ fc2_b,
    float* __restrict__ y)
{
    __shared__ __align__(16) char smem[81920];
    bf16* const h2    = (bf16*)smem;     // [64][128] bf16, 256B rows
    char* const abase = smem + 16384;    // [64][512] bf16, 1024B rows

    const int tid  = threadIdx.x;
    const int wave = tid >> 6;
    const int lane = tid & 63;
    const int g = lane >> 4;
    const int c = lane & 15;
    const size_t t0 = (size_t)blockIdx.x * 64;

    // LN2 over 64 tokens
    {
        const int slot = tid >> 5, l32 = tid & 31;
        for (int it = 0; it < 8; ++it) {
            int t = slot + (it << 3);                   // 0..63
            const float* src = y + ((t0 + t) << 7) + (l32 << 2);
            float4 v = *(const float4*)src;
            float s  = v.x + v.y + v.z + v.w;
            float s2 = v.x * v.x + v.y * v.y + v.z * v.z + v.w * v.w;
            for (int m = 1; m <= 16; m <<= 1) {
                s  += __shfl_xor(s,  m, 64);
                s2 += __shfl_xor(s2, m, 64);
            }
            float mean = s * (1.0f / 128.0f);
            float var  = s2 * (1.0f / 128.0f) - mean * mean;
            float rs   = rsqrtf(var + 1e-5f);
            float4 wv = *(const float4*)(n2w + (l32 << 2));
            float4 bv = *(const float4*)(n2b + (l32 << 2));
            bf16x4 outv;
            outv[0] = (bf16)((v.x - mean) * rs * wv.x + bv.x);
            outv[1] = (bf16)((v.y - mean) * rs * wv.y + bv.y);
            outv[2] = (bf16)((v.z - mean) * rs * wv.z + bv.z);
            outv[3] = (bf16)((v.w - mean) * rs * wv.w + bv.w);
            int off = (l32 << 3) ^ ((t & 7) << 4);
            *(bf16x4*)((char*)h2 + t * 256 + off) = outv;
        }
    }
    __syncthreads();

    // fc1: each wave computes 128 hidden cols for all 64 rows, in TWO 64-col
    // passes (spill fix: a1[4][8]=128 live floats was spilling 640 B/thread).
    f32x4 fz = {0.f, 0.f, 0.f, 0.f};
    #pragma unroll 1
    for (int half = 0; half < 2; ++half) {
        f32x4 a1[4][4];
        #pragma unroll
        for (int mt = 0; mt < 4; ++mt) for (int nt = 0; nt < 4; ++nt) a1[mt][nt] = fz;
        #pragma unroll
        for (int ks = 0; ks < 4; ++ks) {
            bf16x8 af[4];
            int koff = ks * 64 + g * 16;
            #pragma unroll
            for (int mt = 0; mt < 4; ++mt) {
                int row = mt * 16 + c;
                af[mt] = *(const bf16x8*)((char*)h2 + row * 256 + (koff ^ ((row & 7) << 4)));
            }
            #pragma unroll
            for (int nt = 0; nt < 4; ++nt) {
                int col = wave * 128 + half * 64 + nt * 16 + c;
                bf16x8 bw = *(const bf16x8*)(fc1wp + (((ks * 512 + col) * 4 + g) << 3));
                #pragma unroll
                for (int mt = 0; mt < 4; ++mt) a1[mt][nt] = mfma16(af[mt], bw, a1[mt][nt]);
            }
        }
        #pragma unroll
        for (int nt = 0; nt < 4; ++nt) {
            int col = wave * 128 + half * 64 + nt * 16 + c;
            float fb = fc1_b[col];
            #pragma unroll
            for (int mt = 0; mt < 4; ++mt)
                #pragma unroll
                for (int r = 0; r < 4; ++r) {
                    int row = mt * 16 + g * 4 + r;
                    float ge = gelu_f(a1[mt][nt][r] + fb);
                    *(bf16*)(abase + row * 1024 + ((col * 2) ^ ((row & 7) << 4))) = (bf16)ge;
                }
        }
    }
    __syncthreads();

    // fc2: each wave computes 32 output cols; K = 512 (a2 = 32 live floats)
    f32x4 a2[4][2];
    for (int mt = 0; mt < 4; ++mt) for (int nt = 0; nt < 2; ++nt) a2[mt][nt] = fz;
    #pragma unroll 1
    for (int ks = 0; ks < 16; ++ks) {
        bf16x8 af[4];
        int koff = ks * 64 + g * 16;
        #pragma unroll
        for (int mt = 0; mt < 4; ++mt) {
            int row = mt * 16 + c;
            af[mt] = *(const bf16x8*)(abase + row * 1024 + (koff ^ ((row & 7) << 4)));
        }
        #pragma unroll
        for (int nt = 0; nt < 2; ++nt) {
            int col = wave * 32 + nt * 16 + c;
            bf16x8 bw = *(const bf16x8*)(fc2wp + (((ks * 128 + col) * 4 + g) << 3));
            #pragma unroll
            for (int mt = 0; mt < 4; ++mt) a2[mt][nt] = mfma16(af[mt], bw, a2[mt][nt]);
        }
    }
    for (int nt = 0; nt < 2; ++nt) {
        int col = wave * 32 + nt * 16 + c;
        float fb = fc2_b[col];
        for (int mt = 0; mt < 4; ++mt)
            for (int r = 0; r < 4; ++r) {
                int row = mt * 16 + g * 4 + r;
                size_t idx = ((t0 + row) << 7) + col;
                y[idx] = y[idx] + a2[mt][nt][r] + fb;   // residual, in place
            }
    }
}

// ---------------- launch ----------------

extern "C" void kernel_launch(void* const* d_in, const int* in_sizes, int n_in,
                              void* d_out, int out_size, void* d_ws, size_t ws_size,
                              hipStream_t stream) {
    const float* x        = (const float*)d_in[0];
    // d_in[1] attn_mask: unused by the reference (faithful)
    const float* n1w      = (const float*)d_in[2];
    const float* n1b      = (const float*)d_in[3];
    const float* qkv_w    = (const float*)d_in[4];
    const float* qkv_b    = (const float*)d_in[5];
    const float* rel_tab  = (const float*)d_in[6];
    const int*   rel_idx  = (const int*)d_in[7];
    const float* proj_w   = (const float*)d_in[8];
    const float* proj_b   = (const float*)d_in[9];
    const float* n2w      = (const float*)d_in[10];
    const float* n2b      = (const float*)d_in[11];
    const float* fc1_w    = (const float*)d_in[12];
    const float* fc1_b    = (const float*)d_in[13];
    const float* fc2_w    = (const float*)d_in[14];
    const float* fc2_b    = (const float*)d_in[15];

    float* yout = (float*)d_out;
    char*  ws   = (char*)d_ws;
    float* biasbuf = (float*)(ws + WS_BIAS);
    bf16*  qkvwp = (bf16*)(ws + WS_QKVW);
    bf16*  projwp= (bf16*)(ws + WS_PROJW);
    bf16*  fc1wp = (bf16*)(ws + WS_FC1W);
    bf16*  fc2wp = (bf16*)(ws + WS_FC2W);

    bias_kernel<<<dim3(49), dim3(256), 0, stream>>>(rel_tab, rel_idx, biasbuf);
    wcvt_kernel<<<dim3(768), dim3(256), 0, stream>>>(qkv_w, proj_w, fc1_w, fc2_w,
                                                     qkvwp, projwp, fc1wp, fc2wp);
    attn_kernel<<<dim3(2048), dim3(256), 0, stream>>>(x, n1w, n1b, qkvwp, qkv_b,
                                                      projwp, proj_b, biasbuf, yout);
    mlp_kernel<<<dim3(1568), dim3(256), 0, stream>>>(n2w, n2b, fc1wp, fc1_b,
                                                     fc2wp, fc2_b, yout);
}

// Round 6
// 257.743 us; speedup vs baseline: 1.2218x; 1.0763x over previous
//
#include <hip/hip_runtime.h>

typedef __bf16 bf16;
typedef __bf16 bf16x4 __attribute__((ext_vector_type(4)));
typedef __bf16 bf16x8 __attribute__((ext_vector_type(8)));
typedef float f32x4 __attribute__((ext_vector_type(4)));

#define NTOK 49
#define HW 56
#define SHIFT3 3
constexpr float kScale = 0.17677669529663687f;  // 32^-0.5

// ws layout (bytes, 16B aligned)
#define WS_BIAS  0        // f32 [4*49*64]   = 50176 B
#define WS_QKVW  50176    // bf16[49152] packed [ks4][row384][g4][8]
#define WS_PROJW 148480   // bf16[16384] packed [ks4][col128][g4][8]
#define WS_FC1W  181248   // bf16[65536] packed [ks4][col512][g4][8]
#define WS_FC2W  312320   // bf16[65536] packed [ks16][col128][g4][8]

// D[i][j] = sum_k A[i][k]*B[j][k] + C ; lane: A/B row = l&15, k = (l>>4)*8..+8
// D: col j = l&15, row i = (l>>4)*4 + r  (verified by R1-R5 passing kernels)
static __device__ __forceinline__ f32x4 mfma16(bf16x8 a, bf16x8 b, f32x4 c) {
    return __builtin_amdgcn_mfma_f32_16x16x32_bf16(a, b, c, 0, 0, 0);
}

static __device__ __forceinline__ float gelu_f(float x) {
    float x2 = x * x;
    float u2 = x * (1.5957691216f + 0.0713548162f * x2);   // 2u
    return x / (1.0f + __expf(-u2));
}

// ---------------- setup kernels ----------------

__global__ void bias_kernel(const float* __restrict__ rel_table,
                            const int* __restrict__ rel_index,
                            float* __restrict__ biasbuf) {
    int idx = blockIdx.x * 256 + threadIdx.x;     // over 4*49*64 = 12544
    if (idx >= 4 * NTOK * 64) return;
    int j = idx & 63;
    int rest = idx >> 6;
    int i = rest % NTOK;
    int h = rest / NTOK;
    float v = -1e30f;                             // masks j >= 49 (K padding)
    if (j < NTOK) v = rel_table[rel_index[i * NTOK + j] * 4 + h];
    biasbuf[idx] = v;
}

__global__ void wcvt_kernel(const float* __restrict__ qkv_w, const float* __restrict__ proj_w,
                            const float* __restrict__ fc1_w, const float* __restrict__ fc2_w,
                            bf16* __restrict__ qkvwp, bf16* __restrict__ projwp,
                            bf16* __restrict__ fc1wp, bf16* __restrict__ fc2wp) {
    int idx = blockIdx.x * 256 + threadIdx.x;     // 768*256 = 196608 exactly
    if (idx < 49152) {
        int o = idx, e = o & 7, t = o >> 3, g = t & 3; t >>= 2;
        int row = t % 384, ks = t / 384;
        qkvwp[o] = (bf16)qkv_w[row * 128 + ks * 32 + g * 8 + e];
    } else if (idx < 65536) {
        int o = idx - 49152, e = o & 7, t = o >> 3, g = t & 3; t >>= 2;
        int row = t % 128, ks = t / 128;
        projwp[o] = (bf16)proj_w[row * 128 + ks * 32 + g * 8 + e];
    } else if (idx < 131072) {
        int o = idx - 65536, e = o & 7, t = o >> 3, g = t & 3; t >>= 2;
        int row = t % 512, ks = t / 512;
        fc1wp[o] = (bf16)fc1_w[row * 128 + ks * 32 + g * 8 + e];
    } else {
        int o = idx - 131072, e = o & 7, t = o >> 3, g = t & 3; t >>= 2;
        int row = t % 128, ks = t / 128;
        fc2wp[o] = (bf16)fc2_w[row * 512 + ks * 32 + g * 8 + e];
    }
}

// ---------------- fused attention (per-window) ----------------
// block = one 7x7 window; 4 waves = 4 heads. LDS 64KB -> 2 blocks/CU.
// All GEMMs use weight/K as A-operand so C-fragments are channel-contiguous
// per token -> vectorized epilogues (bf16x4 LDS, float4 global).

__global__ __launch_bounds__(256, 2) void attn_kernel(
    const float* __restrict__ x,
    const float* __restrict__ n1w, const float* __restrict__ n1b,
    const bf16*  __restrict__ qkvwp, const float* __restrict__ qkv_b,
    const bf16*  __restrict__ projwp, const float* __restrict__ proj_b,
    const float* __restrict__ biasbuf,
    float* __restrict__ yout)
{
    __shared__ __align__(16) char smem[65536];
    bf16* const hb = (bf16*)smem;                       // h / ao: [64][128] bf16, 256B rows

    const int tid  = threadIdx.x;
    const int wave = tid >> 6;
    const int lane = tid & 63;
    const int g = lane >> 4;     // 0..3
    const int c = lane & 15;     // 0..15

    char* const qbase  = smem + 16384 + wave * 8192;    // q [64][32] bf16, 64B rows
    char* const kbase  = qbase + 4096;                  // k [64][32]
    char* const pbase  = qbase;                         // P [64][64] 128B rows (overlays q+k)
    char* const vtbase = smem + 49152 + wave * 4096;    // vT [32][64] 128B rows

    const int w  = blockIdx.x;
    const int b  = w >> 6;
    const int wi = (w >> 3) & 7;
    const int wj = w & 7;
    const int head = wave;

    // ---- stage 0: LN1 + shifted-window gather -> hb (rows 49..63 zeroed) ----
    {
        const int slot = tid >> 5, l32 = tid & 31;
        for (int it = 0; it < 8; ++it) {
            int t  = slot + (it << 3);                  // 0..63
            int tt = t < NTOK ? t : NTOK - 1;
            int r  = tt / 7, cc = tt - r * 7;
            int row = wi * 7 + r + SHIFT3;  if (row >= HW) row -= HW;
            int col = wj * 7 + cc + SHIFT3; if (col >= HW) col -= HW;
            const float* src = x + (((size_t)(b * 3136 + row * 56 + col)) << 7) + (l32 << 2);
            float4 v = *(const float4*)src;
            float s  = v.x + v.y + v.z + v.w;
            float s2 = v.x * v.x + v.y * v.y + v.z * v.z + v.w * v.w;
            for (int m = 1; m <= 16; m <<= 1) {
                s  += __shfl_xor(s,  m, 64);
                s2 += __shfl_xor(s2, m, 64);
            }
            float mean = s * (1.0f / 128.0f);
            float var  = s2 * (1.0f / 128.0f) - mean * mean;
            float rs   = rsqrtf(var + 1e-5f);
            float4 wv = *(const float4*)(n1w + (l32 << 2));
            float4 bv = *(const float4*)(n1b + (l32 << 2));
            bf16x4 outv;
            if (t < NTOK) {
                outv[0] = (bf16)((v.x - mean) * rs * wv.x + bv.x);
                outv[1] = (bf16)((v.y - mean) * rs * wv.y + bv.y);
                outv[2] = (bf16)((v.z - mean) * rs * wv.z + bv.z);
                outv[3] = (bf16)((v.w - mean) * rs * wv.w + bv.w);
            } else {
                outv[0] = (bf16)0.0f; outv[1] = (bf16)0.0f;
                outv[2] = (bf16)0.0f; outv[3] = (bf16)0.0f;
            }
            int off = (l32 << 3) ^ ((t & 7) << 4);
            *(bf16x4*)((char*)hb + t * 256 + off) = outv;
        }
    }
    __syncthreads();

    // ---- stage 1: qkv. q,k swapped-role (D: row=dl, col=tok); v original ----
    f32x4 fz = {0.f, 0.f, 0.f, 0.f};
    #pragma unroll 1
    for (int nt = 0; nt < 2; ++nt) {
        f32x4 qa[4], ka[4], va[4];
        #pragma unroll
        for (int mt = 0; mt < 4; ++mt) { qa[mt] = fz; ka[mt] = fz; va[mt] = fz; }

        #pragma unroll
        for (int ks = 0; ks < 4; ++ks) {
            bf16x8 af[4];
            const int koff = ks * 64 + g * 16;
            #pragma unroll
            for (int mt = 0; mt < 4; ++mt) {
                int row = mt * 16 + c;
                af[mt] = *(const bf16x8*)((char*)hb + row * 256 + (koff ^ ((row & 7) << 4)));
            }
            int jb = head * 32 + nt * 16 + c;
            bf16x8 bq = *(const bf16x8*)(qkvwp + (((ks * 384 + jb) * 4 + g) << 3));
            bf16x8 bk = *(const bf16x8*)(qkvwp + (((ks * 384 + 128 + jb) * 4 + g) << 3));
            bf16x8 bv = *(const bf16x8*)(qkvwp + (((ks * 384 + 256 + jb) * 4 + g) << 3));
            #pragma unroll
            for (int mt = 0; mt < 4; ++mt) {
                qa[mt] = mfma16(bq, af[mt], qa[mt]);    // swapped: A=weight
                ka[mt] = mfma16(bk, af[mt], ka[mt]);    // swapped
                va[mt] = mfma16(af[mt], bv, va[mt]);    // original: A=tokens
            }
        }
        // vectorized epilogue
        f32x4 qb4 = *(const f32x4*)(qkv_b + head * 32 + nt * 16 + g * 4);
        f32x4 kb4 = *(const f32x4*)(qkv_b + 128 + head * 32 + nt * 16 + g * 4);
        float vb  = qkv_b[256 + head * 32 + nt * 16 + c];
        #pragma unroll
        for (int mt = 0; mt < 4; ++mt) {
            // q,k: lane holds tok=mt*16+c, dl=nt*16+g*4+r (4 consecutive dl)
            int tok = mt * 16 + c;
            bf16x4 qv, kv;
            #pragma unroll
            for (int r = 0; r < 4; ++r) {
                qv[r] = (bf16)(qa[mt][r] + qb4[r]);
                kv[r] = (bf16)(ka[mt][r] + kb4[r]);
            }
            int qoff = (nt * 32 + g * 8) ^ ((tok & 3) << 4);
            *(bf16x4*)(qbase + tok * 64 + qoff) = qv;
            *(bf16x4*)(kbase + tok * 64 + qoff) = kv;
            // vT: lane holds dl=nt*16+c, tok=mt*16+g*4+r (4 consecutive tok)
            int dl = nt * 16 + c;
            bf16x4 vv;
            #pragma unroll
            for (int r = 0; r < 4; ++r) vv[r] = (bf16)(va[mt][r] + vb);
            *(bf16x4*)(vtbase + dl * 128 + ((mt * 32 + g * 8) ^ ((dl & 7) << 4))) = vv;
        }
    }
    __syncthreads();   // all h reads done (hb reused for ao below)

    // ---- stage 2: S^T tiles: mfma(A=k, B=q) -> lane: qtok=bm*16+c, ktok=bn*16+g*4+r ----
    f32x4 s[4][4];     // [bm][bn]
    #pragma unroll
    for (int bm = 0; bm < 4; ++bm) for (int bn = 0; bn < 4; ++bn) s[bm][bn] = fz;
    {
        bf16x8 aq[4];
        #pragma unroll
        for (int bm = 0; bm < 4; ++bm) {
            int row = bm * 16 + c;
            aq[bm] = *(const bf16x8*)(qbase + row * 64 + ((g * 16) ^ ((row & 3) << 4)));
        }
        #pragma unroll
        for (int bn = 0; bn < 4; ++bn) {
            int row = bn * 16 + c;
            bf16x8 kf = *(const bf16x8*)(kbase + row * 64 + ((g * 16) ^ ((row & 3) << 4)));
            #pragma unroll
            for (int bm = 0; bm < 4; ++bm) s[bm][bn] = mfma16(kf, aq[bm], s[bm][bn]);
        }
    }

    // ---- stage 3: softmax per qtok row; reduce over ktok = in-thread 16 + shfl g ----
    const float* bbase = biasbuf + head * (NTOK * 64);
    float linv[4];
    #pragma unroll
    for (int bm = 0; bm < 4; ++bm) {
        int qt = bm * 16 + c;
        int im = qt < NTOK ? qt : NTOK - 1;
        const float* brow = bbase + im * 64;
        f32x4 vals[4];
        float mx = -3e38f;
        #pragma unroll
        for (int bn = 0; bn < 4; ++bn) {
            f32x4 b4 = *(const f32x4*)(brow + bn * 16 + g * 4);
            #pragma unroll
            for (int r = 0; r < 4; ++r) {
                float v = s[bm][bn][r] * kScale + b4[r];
                vals[bn][r] = v;
                mx = fmaxf(mx, v);
            }
        }
        mx = fmaxf(mx, __shfl_xor(mx, 16, 64));
        mx = fmaxf(mx, __shfl_xor(mx, 32, 64));
        float sum = 0.f;
        #pragma unroll
        for (int bn = 0; bn < 4; ++bn) {
            bf16x4 pv;
            #pragma unroll
            for (int r = 0; r < 4; ++r) {
                float p = __expf(vals[bn][r] - mx);
                sum += p;
                pv[r] = (bf16)p;
            }
            *(bf16x4*)(pbase + qt * 128 + ((bn * 32 + g * 8) ^ ((c & 7) << 4))) = pv;
        }
        sum += __shfl_xor(sum, 16, 64);
        sum += __shfl_xor(sum, 32, 64);
        linv[bm] = 1.0f / sum;
    }

    // ---- stage 4: O^T tiles: mfma(A=vT, B=P) -> lane: qtok=mt*16+c, dd=nt*16+g*4+r ----
    f32x4 o[4][2];
    #pragma unroll
    for (int mt = 0; mt < 4; ++mt) for (int nt = 0; nt < 2; ++nt) o[mt][nt] = fz;
    #pragma unroll
    for (int ks = 0; ks < 2; ++ks) {
        int koff = ks * 64 + g * 16;
        bf16x8 vf[2], pf[4];
        #pragma unroll
        for (int nt = 0; nt < 2; ++nt)
            vf[nt] = *(const bf16x8*)(vtbase + (nt * 16 + c) * 128 + (koff ^ ((c & 7) << 4)));
        #pragma unroll
        for (int mt = 0; mt < 4; ++mt)
            pf[mt] = *(const bf16x8*)(pbase + (mt * 16 + c) * 128 + (koff ^ ((c & 7) << 4)));
        #pragma unroll
        for (int mt = 0; mt < 4; ++mt)
            #pragma unroll
            for (int nt = 0; nt < 2; ++nt) o[mt][nt] = mfma16(vf[nt], pf[mt], o[mt][nt]);
    }
    // normalize + vector ao write into hb
    #pragma unroll
    for (int mt = 0; mt < 4; ++mt) {
        int qt = mt * 16 + c;
        if (qt < NTOK) {
            float inv = linv[mt];
            #pragma unroll
            for (int nt = 0; nt < 2; ++nt) {
                bf16x4 ov;
                #pragma unroll
                for (int r = 0; r < 4; ++r) ov[r] = (bf16)(o[mt][nt][r] * inv);
                int coff = (head * 64 + nt * 32 + g * 8) ^ ((qt & 7) << 4);
                *(bf16x4*)((char*)hb + qt * 256 + coff) = ov;
            }
        }
    }
    __syncthreads();

    // ---- stage 5: proj swapped (A=weight) + float4 residual scatter ----
    f32x4 pj[4][2];
    #pragma unroll
    for (int mt = 0; mt < 4; ++mt) for (int nt = 0; nt < 2; ++nt) pj[mt][nt] = fz;
    #pragma unroll
    for (int ks = 0; ks < 4; ++ks) {
        bf16x8 af[4];
        int koff = ks * 64 + g * 16;
        #pragma unroll
        for (int mt = 0; mt < 4; ++mt) {
            int row = mt * 16 + c;
            af[mt] = *(const bf16x8*)((char*)hb + row * 256 + (koff ^ ((row & 7) << 4)));
        }
        #pragma unroll
        for (int nt = 0; nt < 2; ++nt) {
            int colw = wave * 32 + nt * 16 + c;
            bf16x8 bp = *(const bf16x8*)(projwp + (((ks * 128 + colw) * 4 + g) << 3));
            #pragma unroll
            for (int mt = 0; mt < 4; ++mt) pj[mt][nt] = mfma16(bp, af[mt], pj[mt][nt]);
        }
    }
    f32x4 pb0 = *(const f32x4*)(proj_b + wave * 32 + g * 4);
    f32x4 pb1 = *(const f32x4*)(proj_b + wave * 32 + 16 + g * 4);
    #pragma unroll
    for (int mt = 0; mt < 4; ++mt) {
        int qt = mt * 16 + c;
        if (qt < NTOK) {
            int rr = qt / 7, cc = qt - rr * 7;
            int row = wi * 7 + rr + SHIFT3;  if (row >= HW) row -= HW;
            int col = wj * 7 + cc + SHIFT3;  if (col >= HW) col -= HW;
            size_t base = ((size_t)(b * 3136 + row * 56 + col)) << 7;
            int c0 = wave * 32 + g * 4;
            f32x4 x0 = *(const f32x4*)(x + base + c0);
            f32x4 x1 = *(const f32x4*)(x + base + c0 + 16);
            f32x4 y0 = x0 + pj[mt][0] + pb0;
            f32x4 y1 = x1 + pj[mt][1] + pb1;
            *(f32x4*)(yout + base + c0)      = y0;
            *(f32x4*)(yout + base + c0 + 16) = y1;
        }
    }
}

// ---------------- MLP: LN2 -> fc1+gelu -> fc2 -> +residual (in-place) ----------------
// BM=32 tokens/block, 3136 blocks. LDS 32KB (act overlays h2) -> 4+ blocks/CU.

__global__ __launch_bounds__(256, 4) void mlp_kernel(
    const float* __restrict__ n2w, const float* __restrict__ n2b,
    const bf16*  __restrict__ fc1wp, const float* __restrict__ fc1_b,
    const bf16*  __restrict__ fc2wp, const float* __restrict__ fc2_b,
    float* __restrict__ y)
{
    __shared__ __align__(16) char smem[32768];
    bf16* const h2    = (bf16*)smem;     // [32][128] bf16, 256B rows (dead after fc1)
    char* const abase = smem;            // act [32][512] bf16, 1024B rows (overlays h2)

    const int tid  = threadIdx.x;
    const int wave = tid >> 6;
    const int lane = tid & 63;
    const int g = lane >> 4;
    const int c = lane & 15;
    const size_t t0 = (size_t)blockIdx.x * 32;

    // LN2 over 32 tokens
    {
        const int slot = tid >> 5, l32 = tid & 31;
        for (int it = 0; it < 4; ++it) {
            int t = slot + (it << 3);                   // 0..31
            const float* src = y + ((t0 + t) << 7) + (l32 << 2);
            float4 v = *(const float4*)src;
            float s  = v.x + v.y + v.z + v.w;
            float s2 = v.x * v.x + v.y * v.y + v.z * v.z + v.w * v.w;
            for (int m = 1; m <= 16; m <<= 1) {
                s  += __shfl_xor(s,  m, 64);
                s2 += __shfl_xor(s2, m, 64);
            }
            float mean = s * (1.0f / 128.0f);
            float var  = s2 * (1.0f / 128.0f) - mean * mean;
            float rs   = rsqrtf(var + 1e-5f);
            float4 wv = *(const float4*)(n2w + (l32 << 2));
            float4 bv = *(const float4*)(n2b + (l32 << 2));
            bf16x4 outv;
            outv[0] = (bf16)((v.x - mean) * rs * wv.x + bv.x);
            outv[1] = (bf16)((v.y - mean) * rs * wv.y + bv.y);
            outv[2] = (bf16)((v.z - mean) * rs * wv.z + bv.z);
            outv[3] = (bf16)((v.w - mean) * rs * wv.w + bv.w);
            int off = (l32 << 3) ^ ((t & 7) << 4);
            *(bf16x4*)((char*)h2 + t * 256 + off) = outv;
        }
    }
    __syncthreads();

    // fc1 swapped (A=weight): wave computes 128 hidden cols x 32 tokens, acc in regs
    f32x4 fz = {0.f, 0.f, 0.f, 0.f};
    f32x4 a1[8][2];   // [nt][mt] : lane holds tok=mt*16+c, hid=nt*16+g*4+r
    #pragma unroll
    for (int nt = 0; nt < 8; ++nt) for (int mt = 0; mt < 2; ++mt) a1[nt][mt] = fz;
    #pragma unroll
    for (int ks = 0; ks < 4; ++ks) {
        bf16x8 af[2];
        int koff = ks * 64 + g * 16;
        #pragma unroll
        for (int mt = 0; mt < 2; ++mt) {
            int row = mt * 16 + c;
            af[mt] = *(const bf16x8*)((char*)h2 + row * 256 + (koff ^ ((row & 7) << 4)));
        }
        #pragma unroll
        for (int nt = 0; nt < 8; ++nt) {
            int col = wave * 128 + nt * 16 + c;
            bf16x8 bw = *(const bf16x8*)(fc1wp + (((ks * 512 + col) * 4 + g) << 3));
            #pragma unroll
            for (int mt = 0; mt < 2; ++mt) a1[nt][mt] = mfma16(bw, af[mt], a1[nt][mt]);
        }
    }
    __syncthreads();   // h2 fully consumed; act may now overlay it

    // gelu + vector act write
    #pragma unroll
    for (int nt = 0; nt < 8; ++nt) {
        f32x4 fb4 = *(const f32x4*)(fc1_b + wave * 128 + nt * 16 + g * 4);
        #pragma unroll
        for (int mt = 0; mt < 2; ++mt) {
            int tok = mt * 16 + c;
            bf16x4 gv;
            #pragma unroll
            for (int r = 0; r < 4; ++r) gv[r] = (bf16)gelu_f(a1[nt][mt][r] + fb4[r]);
            int coff = (wave * 256 + nt * 32 + g * 8) ^ ((tok & 7) << 4);
            *(bf16x4*)(abase + tok * 1024 + coff) = gv;
        }
    }
    __syncthreads();

    // fc2 swapped (A=weight): wave computes 32 out cols; K=512
    f32x4 a2[2][2];   // [nt][mt]
    #pragma unroll
    for (int nt = 0; nt < 2; ++nt) for (int mt = 0; mt < 2; ++mt) a2[nt][mt] = fz;
    #pragma unroll 4
    for (int ks = 0; ks < 16; ++ks) {
        bf16x8 af[2];
        int koff = ks * 64 + g * 16;
        #pragma unroll
        for (int mt = 0; mt < 2; ++mt) {
            int row = mt * 16 + c;
            af[mt] = *(const bf16x8*)(abase + row * 1024 + (koff ^ ((row & 7) << 4)));
        }
        #pragma unroll
        for (int nt = 0; nt < 2; ++nt) {
            int col = wave * 32 + nt * 16 + c;
            bf16x8 bw = *(const bf16x8*)(fc2wp + (((ks * 128 + col) * 4 + g) << 3));
            #pragma unroll
            for (int mt = 0; mt < 2; ++mt) a2[nt][mt] = mfma16(bw, af[mt], a2[nt][mt]);
        }
    }
    // float4 residual epilogue: lane holds tok=mt*16+c, outch=wave*32+nt*16+g*4..+4
    #pragma unroll
    for (int nt = 0; nt < 2; ++nt) {
        f32x4 fb4 = *(const f32x4*)(fc2_b + wave * 32 + nt * 16 + g * 4);
        #pragma unroll
        for (int mt = 0; mt < 2; ++mt) {
            size_t idx = ((t0 + mt * 16 + c) << 7) + wave * 32 + nt * 16 + g * 4;
            f32x4 yv = *(const f32x4*)(y + idx);
            yv = yv + a2[nt][mt] + fb4;
            *(f32x4*)(y + idx) = yv;
        }
    }
}

// ---------------- launch ----------------

extern "C" void kernel_launch(void* const* d_in, const int* in_sizes, int n_in,
                              void* d_out, int out_size, void* d_ws, size_t ws_size,
                              hipStream_t stream) {
    const float* x        = (const float*)d_in[0];
    // d_in[1] attn_mask: unused by the reference (faithful)
    const float* n1w      = (const float*)d_in[2];
    const float* n1b      = (const float*)d_in[3];
    const float* qkv_w    = (const float*)d_in[4];
    const float* qkv_b    = (const float*)d_in[5];
    const float* rel_tab  = (const float*)d_in[6];
    const int*   rel_idx  = (const int*)d_in[7];
    const float* proj_w   = (const float*)d_in[8];
    const float* proj_b   = (const float*)d_in[9];
    const float* n2w      = (const float*)d_in[10];
    const float* n2b      = (const float*)d_in[11];
    const float* fc1_w    = (const float*)d_in[12];
    const float* fc1_b    = (const float*)d_in[13];
    const float* fc2_w    = (const float*)d_in[14];
    const float* fc2_b    = (const float*)d_in[15];

    float* yout = (float*)d_out;
    char*  ws   = (char*)d_ws;
    float* biasbuf = (float*)(ws + WS_BIAS);
    bf16*  qkvwp = (bf16*)(ws + WS_QKVW);
    bf16*  projwp= (bf16*)(ws + WS_PROJW);
    bf16*  fc1wp = (bf16*)(ws + WS_FC1W);
    bf16*  fc2wp = (bf16*)(ws + WS_FC2W);

    bias_kernel<<<dim3(49), dim3(256), 0, stream>>>(rel_tab, rel_idx, biasbuf);
    wcvt_kernel<<<dim3(768), dim3(256), 0, stream>>>(qkv_w, proj_w, fc1_w, fc2_w,
                                                     qkvwp, projwp, fc1wp, fc2wp);
    attn_kernel<<<dim3(2048), dim3(256), 0, stream>>>(x, n1w, n1b, qkvwp, qkv_b,
                                                      projwp, proj_b, biasbuf, yout);
    mlp_kernel<<<dim3(3136), dim3(256), 0, stream>>>(n2w, n2b, fc1wp, fc1_b,
                                                     fc2wp, fc2_b, yout);
}